// Round 1
// baseline (486.452 us; speedup 1.0000x reference)
//
#include <hip/hip_runtime.h>
#include <math.h>

// Problem constants (from reference)
#define BSZ   128
#define SSZ   1024
#define HSZ   768
#define MAXV  25
#define SLEVI (SSZ - 2 * MAXV)   // 974

// -----------------------------------------------------------------------------
// Kernel 1: per-batch masked softmax pooling.
// One block per batch, 256 threads (4 waves).
// Scores: sc[t] = dot(hidden[b, s_t, :], align_w[H:2H]).
//   (dot(subject,w1) and align_b are constant across the batch's masked tokens
//    and cancel exactly in softmax(x - max).)
// Then pooled[b,h] = sum_t softmax(sc)[t] * hidden[b, s_t, h].
// -----------------------------------------------------------------------------
__global__ __launch_bounds__(256) void pool_kernel(
    const float* __restrict__ hidden,      // [B,S,H]
    const int*   __restrict__ verb_count,  // [B]
    const float* __restrict__ align_w,     // [2H]
    float*       __restrict__ pooled)      // [B,H] (workspace)
{
    const int b    = blockIdx.x;
    const int tid  = threadIdx.x;
    const int lane = tid & 63;
    const int wave = tid >> 6;

    int v = verb_count[b];
    if (v < 0)    v = 0;
    if (v > MAXV) v = MAXV;
    const int nt = 2 * v;                  // number of masked tokens (<= 48)

    __shared__ float sc [2 * MAXV];
    __shared__ float wts[2 * MAXV];

    const float* __restrict__ w2 = align_w + HSZ;

    // ---- Pass 1: scores (each wave handles tokens t = wave, wave+4, ...) ----
    for (int t = wave; t < nt; t += 4) {
        const int s = (t < v) ? (SLEVI + t) : (SLEVI + MAXV + (t - v));
        const float* __restrict__ row = hidden + ((size_t)b * SSZ + s) * HSZ;
        float acc = 0.0f;
#pragma unroll
        for (int i = 0; i < HSZ / 64; ++i) {
            acc = fmaf(row[lane + 64 * i], w2[lane + 64 * i], acc);
        }
        // wave(64)-wide reduction
#pragma unroll
        for (int off = 32; off > 0; off >>= 1) {
            acc += __shfl_down(acc, off);
        }
        if (lane == 0) sc[t] = acc;
    }
    __syncthreads();

    // ---- Softmax over <=48 scores (serial on thread 0; trivial work) ----
    if (tid == 0 && nt > 0) {
        float m = -INFINITY;
        for (int t = 0; t < nt; ++t) m = fmaxf(m, sc[t]);
        float denom = 0.0f;
        for (int t = 0; t < nt; ++t) {
            const float e = expf(sc[t] - m);
            wts[t] = e;
            denom += e;
        }
        const float inv = 1.0f / denom;    // denom >= 1 (max term contributes exp(0)=1)
        for (int t = 0; t < nt; ++t) wts[t] *= inv;
    }
    __syncthreads();

    // ---- Pass 2: weighted gather-accumulate (rows are L2-hot from pass 1) ----
    float acc0 = 0.0f, acc1 = 0.0f, acc2 = 0.0f;
    for (int t = 0; t < nt; ++t) {
        const int s = (t < v) ? (SLEVI + t) : (SLEVI + MAXV + (t - v));
        const float w = wts[t];            // LDS broadcast (uniform address)
        const float* __restrict__ row = hidden + ((size_t)b * SSZ + s) * HSZ;
        acc0 = fmaf(w, row[tid          ], acc0);
        acc1 = fmaf(w, row[tid + 256    ], acc1);
        acc2 = fmaf(w, row[tid + 512    ], acc2);
    }
    float* dst = pooled + (size_t)b * HSZ;
    dst[tid      ] = acc0;
    dst[tid + 256] = acc1;
    dst[tid + 512] = acc2;
}

// -----------------------------------------------------------------------------
// Kernel 2: out[b,i] = tanh( dot(pooled[b,:], out_w[i,:]) + out_b[i] )
// Grid: (HSZ/256 = 3 output chunks, BSZ/4 = 32 batch groups), 256 threads.
// Each thread owns 1 output feature x 4 batches: streams its out_w row as
// float4 (per-lane contiguous, L2-resident across blocks); pooled reads are
// uniform-address (scalarizable).
// -----------------------------------------------------------------------------
#define BPB 4   // batches per block

__global__ __launch_bounds__(256) void gemv_tanh_kernel(
    const float* __restrict__ pooled,   // [B,H]
    const float* __restrict__ out_w,    // [H,H] row-major: out_w[i*H + j]
    const float* __restrict__ out_b,    // [H]
    float*       __restrict__ out)      // [B,H]
{
    const int i  = blockIdx.x * 256 + threadIdx.x;  // output feature
    const int b0 = blockIdx.y * BPB;                // first batch of group

    const float* __restrict__ wrow = out_w + (size_t)i * HSZ;

    float acc[BPB];
#pragma unroll
    for (int bb = 0; bb < BPB; ++bb) acc[bb] = 0.0f;

    for (int j = 0; j < HSZ; j += 4) {
        const float4 w4 = *(const float4*)(wrow + j);
#pragma unroll
        for (int bb = 0; bb < BPB; ++bb) {
            const float4 p4 = *(const float4*)(pooled + (size_t)(b0 + bb) * HSZ + j);
            acc[bb] = fmaf(w4.x, p4.x, acc[bb]);
            acc[bb] = fmaf(w4.y, p4.y, acc[bb]);
            acc[bb] = fmaf(w4.z, p4.z, acc[bb]);
            acc[bb] = fmaf(w4.w, p4.w, acc[bb]);
        }
    }

    const float bias = out_b[i];
#pragma unroll
    for (int bb = 0; bb < BPB; ++bb) {
        out[(size_t)(b0 + bb) * HSZ + i] = tanhf(acc[bb] + bias);
    }
}

// -----------------------------------------------------------------------------
// Launch
// inputs: 0 hidden(B,S,H) f32 | 1 verb_count(B) int | 2 subject_hidden(B,H) f32
//         3 align_w(1,2H) f32 | 4 align_b(1) f32 | 5 out_w(H,H) f32 | 6 out_b(H) f32
// subject_hidden / align_b / align_w[:H] cancel in softmax -> never read.
// -----------------------------------------------------------------------------
extern "C" void kernel_launch(void* const* d_in, const int* in_sizes, int n_in,
                              void* d_out, int out_size, void* d_ws, size_t ws_size,
                              hipStream_t stream) {
    const float* hidden     = (const float*)d_in[0];
    const int*   verb_count = (const int*)  d_in[1];
    const float* align_w    = (const float*)d_in[3];
    const float* out_w      = (const float*)d_in[5];
    const float* out_b      = (const float*)d_in[6];
    float*       out        = (float*)d_out;
    float*       pooled     = (float*)d_ws;     // B*H*4 = 384 KiB scratch

    pool_kernel<<<dim3(BSZ), dim3(256), 0, stream>>>(hidden, verb_count, align_w, pooled);

    gemv_tanh_kernel<<<dim3(HSZ / 256, BSZ / BPB), dim3(256), 0, stream>>>(
        pooled, out_w, out_b, out);
}